// Round 11
// baseline (462.112 us; speedup 1.0000x reference)
//
#include <hip/hip_runtime.h>

#define NB 8
#define NQ 2048
#define NK 2048
#define ND 512
#define QB 32
#define KB 256
#define MASK_VALUE (-1e-06f)
#define PLANE  ((size_t)NB * NK * ND)
#define WPLANE ((size_t)ND * ND)

typedef __attribute__((ext_vector_type(4))) float f32x4;
typedef __attribute__((ext_vector_type(8))) __bf16 bf16x8;
typedef __attribute__((ext_vector_type(8))) _Float16 f16x8;
typedef __attribute__((ext_vector_type(4))) _Float16 f16x4;
typedef __attribute__((ext_vector_type(8))) unsigned short u16x8;
typedef __attribute__((ext_vector_type(4))) unsigned int u32x4;

typedef f32x4  __attribute__((may_alias)) f32x4_ma;
typedef bf16x8 __attribute__((may_alias)) bf16x8_ma;
typedef f16x8  __attribute__((may_alias)) f16x8_ma;
typedef f16x4  __attribute__((may_alias)) f16x4_ma;
typedef u32x4  __attribute__((may_alias)) u32x4_ma;

__device__ __forceinline__ unsigned short f2bf(float x){
    union { float f; unsigned u; } v; v.f = x;
    unsigned r = v.u + 0x7fffu + ((v.u >> 16) & 1u);
    return (unsigned short)(r >> 16);
}
__device__ __forceinline__ float bf2f(unsigned short h){
    union { unsigned u; float f; } v; v.u = ((unsigned)h) << 16;
    return v.f;
}

// ---------------- prep 1: K -> hi/lo fp16 planes, layout [b][k][e] ----------------
__global__ __launch_bounds__(256)
void split_k_f16_kernel(const float* __restrict__ K,
                        _Float16* __restrict__ kh,
                        _Float16* __restrict__ kl)
{
    const size_t i = ((size_t)blockIdx.x * 256 + threadIdx.x) * 4;
    const f32x4 v = *(const f32x4_ma*)(K + i);
    f16x4 h, l;
    #pragma unroll
    for (int c = 0; c < 4; ++c){
        h[c] = (_Float16)v[c];
        l[c] = (_Float16)(v[c] - (float)h[c]);
    }
    *(f16x4_ma*)(kh + i) = h;
    *(f16x4_ma*)(kl + i) = l;
}

// -------- prep 2: V -> single fp16 plane TRANSPOSED, layout [b][d][k] --------
__global__ __launch_bounds__(256)
void transpose_v_f16_kernel(const float* __restrict__ V,
                            _Float16* __restrict__ vt)
{
    __shared__ float t[64][68];
    const int tid = threadIdx.x;
    const int bid = blockIdx.x;
    const int dt  = bid & 7;
    const int kt  = (bid >> 3) & 31;
    const int b   = bid >> 8;
    {
        const int rr = tid >> 4;
        const int c4 = (tid & 15) * 4;
        #pragma unroll
        for (int m4 = 0; m4 < 4; ++m4){
            const int kr = rr + m4*16;
            *(f32x4_ma*)&t[kr][c4] =
                *(const f32x4_ma*)&V[((size_t)b*NK + kt*64 + kr)*ND + dt*64 + c4];
        }
    }
    __syncthreads();
    {
        const int dr = tid >> 2;
        const int kc = (tid & 3) * 16;
        f16x8 v0, v1;
        #pragma unroll
        for (int j = 0; j < 8; ++j) v0[j] = (_Float16)t[kc + j][dr];
        #pragma unroll
        for (int j = 0; j < 8; ++j) v1[j] = (_Float16)t[kc + 8 + j][dr];
        const size_t dst = ((size_t)b*ND + dt*64 + dr)*NK + kt*64 + kc;
        *(f16x8_ma*)(vt + dst)     = v0;
        *(f16x8_ma*)(vt + dst + 8) = v1;
    }
}

// -------- prep 3: W -> hi/lo bf16 planes TRANSPOSED, layout [e][d] --------
__global__ __launch_bounds__(256)
void transpose_split_w_kernel(const float* __restrict__ W,
                              unsigned short* __restrict__ wth,
                              unsigned short* __restrict__ wtl)
{
    __shared__ float t[64][68];
    const int tid = threadIdx.x;
    const int et  = blockIdx.x & 7;
    const int dt  = blockIdx.x >> 3;
    {
        const int rr = tid >> 4;
        const int c4 = (tid & 15) * 4;
        #pragma unroll
        for (int m4 = 0; m4 < 4; ++m4){
            const int dr = rr + m4*16;
            *(f32x4_ma*)&t[dr][c4] =
                *(const f32x4_ma*)&W[(size_t)(dt*64 + dr)*ND + et*64 + c4];
        }
    }
    __syncthreads();
    {
        const int er = tid >> 2;
        const int dc = (tid & 3) * 16;
        unsigned short hh[16], ll[16];
        #pragma unroll
        for (int j = 0; j < 16; ++j){
            const float v = t[dc + j][er];
            const unsigned short h = f2bf(v);
            hh[j] = h;
            ll[j] = f2bf(v - bf2f(h));
        }
        u32x4 h0, h1, l0, l1;
        #pragma unroll
        for (int c = 0; c < 4; ++c){
            h0[c] = (unsigned)hh[2*c]   | ((unsigned)hh[2*c+1] << 16);
            h1[c] = (unsigned)hh[8+2*c] | ((unsigned)hh[9+2*c] << 16);
            l0[c] = (unsigned)ll[2*c]   | ((unsigned)ll[2*c+1] << 16);
            l1[c] = (unsigned)ll[8+2*c] | ((unsigned)ll[9+2*c] << 16);
        }
        const size_t dst = (size_t)(et*64 + er)*ND + dt*64 + dc;
        *(u32x4_ma*)(wth + dst)     = h0;
        *(u32x4_ma*)(wth + dst + 8) = h1;
        *(u32x4_ma*)(wtl + dst)     = l0;
        *(u32x4_ma*)(wtl + dst + 8) = l1;
    }
}

// -------- main fused kernel: 8 waves, QB=32, KB=256, 2 independent blocks/CU --------
__global__ __launch_bounds__(512, 4)
void attn_kernel(const float* __restrict__ Qp, const int* __restrict__ Mp,
                 const _Float16* __restrict__ Kh, const _Float16* __restrict__ Kl,
                 const _Float16* __restrict__ Vt,
                 const unsigned short* __restrict__ Wth, const unsigned short* __restrict__ Wtl,
                 float* __restrict__ Op)
{
    __shared__ _Float16 qw[QB][520];    // 33.3 KB
    __shared__ _Float16 p_b[QB][264];   // 16.9 KB
    __shared__ float wredA[QB][8];      // 1 KB  -> 51.2 KB total, 2 blocks/CU

    const int tid  = threadIdx.x;
    const int lane = tid & 63;
    const int wv   = tid >> 6;              // wave 0..7
    const int lm   = lane & 15;
    const int lg   = lane >> 4;
    const int b    = blockIdx.x & 7;        // batch -> XCD affinity
    const int q0   = (int)(blockIdx.x >> 3) * QB;

    int mk;
    {   // tolerate int64-encoded masks (values >=1, so odd words all-zero => int64)
        const int odd = Mp[1] | Mp[3] | Mp[5] | Mp[7];
        mk = (odd == 0) ? Mp[2*b] : Mp[b];
    }

    // ===== Phase 1: qw[32][512] = Q_tile @ W via bf16 hi/lo 3-term MFMA =====
    // wave wv owns output cols [wv*64, +64)
    {
        f32x4 acc[2][4];
        #pragma unroll
        for (int m2 = 0; m2 < 2; ++m2)
            #pragma unroll
            for (int n2 = 0; n2 < 4; ++n2) acc[m2][n2] = (f32x4){0.f,0.f,0.f,0.f};

        for (int w = 0; w < 16; ++w){
            bf16x8 aH[2], aL[2];
            #pragma unroll
            for (int m2 = 0; m2 < 2; ++m2){
                const float* qp = Qp + ((size_t)b*NQ + q0 + m2*16 + lm)*ND + w*32 + lg*8;
                const f32x4 qa = *(const f32x4_ma*)qp;
                const f32x4 qb = *(const f32x4_ma*)(qp + 4);
                u16x8 hh, ll;
                #pragma unroll
                for (int c = 0; c < 4; ++c){
                    const unsigned short h = f2bf(qa[c]);
                    hh[c] = h; ll[c] = f2bf(qa[c] - bf2f(h));
                }
                #pragma unroll
                for (int c = 0; c < 4; ++c){
                    const unsigned short h = f2bf(qb[c]);
                    hh[4+c] = h; ll[4+c] = f2bf(qb[c] - bf2f(h));
                }
                aH[m2] = __builtin_bit_cast(bf16x8, hh);
                aL[m2] = __builtin_bit_cast(bf16x8, ll);
            }
            __builtin_amdgcn_s_setprio(1);
            #pragma unroll
            for (int n2 = 0; n2 < 4; ++n2){
                const size_t wrow = (size_t)(wv*64 + n2*16 + lm)*ND + w*32 + lg*8;
                const bf16x8 bh = *(const bf16x8_ma*)(Wth + wrow);
                const bf16x8 bl = *(const bf16x8_ma*)(Wtl + wrow);
                #pragma unroll
                for (int m2 = 0; m2 < 2; ++m2){
                    acc[m2][n2] = __builtin_amdgcn_mfma_f32_16x16x32_bf16(aH[m2], bh, acc[m2][n2], 0,0,0);
                    acc[m2][n2] = __builtin_amdgcn_mfma_f32_16x16x32_bf16(aH[m2], bl, acc[m2][n2], 0,0,0);
                    acc[m2][n2] = __builtin_amdgcn_mfma_f32_16x16x32_bf16(aL[m2], bh, acc[m2][n2], 0,0,0);
                }
            }
            __builtin_amdgcn_s_setprio(0);
        }
        // C-scatter (row = lg*4+r, col = lm; m89-verified) -> fp16 qw in LDS
        #pragma unroll
        for (int m2 = 0; m2 < 2; ++m2)
            #pragma unroll
            for (int n2 = 0; n2 < 4; ++n2)
                #pragma unroll
                for (int r = 0; r < 4; ++r)
                    qw[m2*16 + lg*4 + r][wv*64 + n2*16 + lm] = (_Float16)acc[m2][n2][r];
    }
    __syncthreads();

    // ===== Phase 2: flash loop over 8 tiles of 256 keys =====
    float m_run[2][4];
    #pragma unroll
    for (int m2 = 0; m2 < 2; ++m2)
        #pragma unroll
        for (int r = 0; r < 4; ++r) m_run[m2][r] = -3.0e38f;

    f32x4 o_acc[2][4];   // wave's d-slice: [wv*64, +64)
    f32x4 l_acc[2];      // denominator via ones-MFMA (consistent with PV numerator)
    #pragma unroll
    for (int m2 = 0; m2 < 2; ++m2){
        l_acc[m2] = (f32x4){0.f,0.f,0.f,0.f};
        #pragma unroll
        for (int n = 0; n < 4; ++n) o_acc[m2][n] = (f32x4){0.f,0.f,0.f,0.f};
    }

    f16x8 ones;
    #pragma unroll
    for (int j = 0; j < 8; ++j) ones[j] = (_Float16)1.0f;

    // wave owns keys [wv*32, +32) of each tile (two 16-groups kg)
    const _Float16* khb = Kh + ((size_t)b*NK + wv*32 + lm)*ND;
    const _Float16* klb = Kl + ((size_t)b*NK + wv*32 + lm)*ND;
    const size_t vbase = ((size_t)b*ND + wv*64 + lm)*NK + lg*8;

    for (int kt = 0; kt < 8; ++kt){
        const int k0 = kt * KB;
        const size_t koff = (size_t)k0 * ND;

        // ---- QK^T (fp16 2-term): sacc[m2][kg] ----
        f32x4 sacc[2][2];
        #pragma unroll
        for (int m2 = 0; m2 < 2; ++m2)
            #pragma unroll
            for (int kg = 0; kg < 2; ++kg) sacc[m2][kg] = (f32x4){0.f,0.f,0.f,0.f};
        #pragma unroll
        for (int w = 0; w < 16; ++w){
            const int eoff = w*32 + lg*8;
            f16x8 bh[2], bl[2];
            #pragma unroll
            for (int kg = 0; kg < 2; ++kg){
                bh[kg] = *(const f16x8_ma*)(khb + koff + (size_t)kg*16*ND + eoff);
                bl[kg] = *(const f16x8_ma*)(klb + koff + (size_t)kg*16*ND + eoff);
            }
            __builtin_amdgcn_s_setprio(1);
            #pragma unroll
            for (int m2 = 0; m2 < 2; ++m2){
                const f16x8 aQ = *(const f16x8_ma*)&qw[m2*16 + lm][eoff];
                #pragma unroll
                for (int kg = 0; kg < 2; ++kg){
                    sacc[m2][kg] = __builtin_amdgcn_mfma_f32_16x16x32_f16(aQ, bh[kg], sacc[m2][kg], 0,0,0);
                    sacc[m2][kg] = __builtin_amdgcn_mfma_f32_16x16x32_f16(aQ, bl[kg], sacc[m2][kg], 0,0,0);
                }
            }
            __builtin_amdgcn_s_setprio(0);
        }

        // ---- faithful mask (lane-local key: k0 + wv*32 + kg*16 + lm) ----
        float sv[2][2][4];
        #pragma unroll
        for (int kg = 0; kg < 2; ++kg){
            const bool inval = (k0 + wv*32 + kg*16 + lm) >= mk;
            #pragma unroll
            for (int m2 = 0; m2 < 2; ++m2)
                #pragma unroll
                for (int r = 0; r < 4; ++r)
                    sv[m2][kg][r] = inval ? MASK_VALUE : sacc[m2][kg][r];
        }

        // ---- per-wave row max over its 32 keys, publish ----
        float pm[2][4];
        #pragma unroll
        for (int m2 = 0; m2 < 2; ++m2)
            #pragma unroll
            for (int r = 0; r < 4; ++r) pm[m2][r] = fmaxf(sv[m2][0][r], sv[m2][1][r]);
        #pragma unroll
        for (int off = 1; off < 16; off <<= 1)
            #pragma unroll
            for (int m2 = 0; m2 < 2; ++m2)
                #pragma unroll
                for (int r = 0; r < 4; ++r)
                    pm[m2][r] = fmaxf(pm[m2][r], __shfl_xor(pm[m2][r], off, 64));
        if (lm == 0){
            #pragma unroll
            for (int m2 = 0; m2 < 2; ++m2)
                #pragma unroll
                for (int r = 0; r < 4; ++r) wredA[m2*16 + lg*4 + r][wv] = pm[m2][r];
        }
        __syncthreads();

        // ---- mnew + exact defer-max rescale + p -> fp16 LDS ----
        #pragma unroll
        for (int m2 = 0; m2 < 2; ++m2)
            #pragma unroll
            for (int r = 0; r < 4; ++r){
                const int row = m2*16 + lg*4 + r;
                const f32x4 g0 = *(const f32x4_ma*)&wredA[row][0];
                const f32x4 g1 = *(const f32x4_ma*)&wredA[row][4];
                float gm = fmaxf(fmaxf(fmaxf(g0[0],g0[1]),fmaxf(g0[2],g0[3])),
                                 fmaxf(fmaxf(g1[0],g1[1]),fmaxf(g1[2],g1[3])));
                if (gm > m_run[m2][r]){          // exact skip: fsc==1 when gm<=m_run
                    const float fsc = __expf(m_run[m2][r] - gm);
                    m_run[m2][r] = gm;
                    #pragma unroll
                    for (int n = 0; n < 4; ++n) o_acc[m2][n][r] *= fsc;
                    l_acc[m2][r] *= fsc;
                }
                #pragma unroll
                for (int kg = 0; kg < 2; ++kg)
                    p_b[row][wv*32 + kg*16 + lm] = (_Float16)__expf(sv[m2][kg][r] - m_run[m2][r]);
            }
        __syncthreads();

        // ---- PV + ones-MFMA denominator on wave's 64 d-cols ----
        #pragma unroll
        for (int kb = 0; kb < 8; ++kb){
            f16x8 pa[2];
            #pragma unroll
            for (int m2 = 0; m2 < 2; ++m2)
                pa[m2] = *(const f16x8_ma*)&p_b[m2*16 + lm][kb*32 + lg*8];
            f16x8 vv[4];
            #pragma unroll
            for (int n = 0; n < 4; ++n)
                vv[n] = *(const f16x8_ma*)(Vt + vbase + (size_t)n*16*NK + k0 + kb*32);
            __builtin_amdgcn_s_setprio(1);
            #pragma unroll
            for (int m2 = 0; m2 < 2; ++m2){
                #pragma unroll
                for (int n = 0; n < 4; ++n)
                    o_acc[m2][n] = __builtin_amdgcn_mfma_f32_16x16x32_f16(pa[m2], vv[n], o_acc[m2][n], 0,0,0);
                l_acc[m2] = __builtin_amdgcn_mfma_f32_16x16x32_f16(pa[m2], ones, l_acc[m2], 0,0,0);
            }
            __builtin_amdgcn_s_setprio(0);
        }
        __syncthreads();
    }

    // ===== epilogue: normalize with the consistent denominator =====
    #pragma unroll
    for (int m2 = 0; m2 < 2; ++m2){
        float li[4];
        #pragma unroll
        for (int r = 0; r < 4; ++r) li[r] = 1.f / l_acc[m2][r];
        #pragma unroll
        for (int n = 0; n < 4; ++n)
            #pragma unroll
            for (int r = 0; r < 4; ++r)
                Op[((size_t)b*NQ + q0 + m2*16 + lg*4 + r)*ND + wv*64 + n*16 + lm]
                    = o_acc[m2][n][r] * li[r];
    }
}

extern "C" void kernel_launch(void* const* d_in, const int* in_sizes, int n_in,
                              void* d_out, int out_size, void* d_ws, size_t ws_size,
                              hipStream_t stream)
{
    (void)in_sizes; (void)n_in; (void)out_size; (void)ws_size;
    const float* Qp = (const float*)d_in[0];
    const float* Kp = (const float*)d_in[1];
    const float* Vp = (const float*)d_in[2];
    const float* Wp = (const float*)d_in[3];
    const int*   Mp = (const int*)  d_in[4];
    float* Op = (float*)d_out;

    unsigned short* wsu = (unsigned short*)d_ws;
    _Float16*       Kh  = (_Float16*)wsu;
    _Float16*       Kl  = (_Float16*)(wsu + PLANE);
    _Float16*       Vt  = (_Float16*)(wsu + 2*PLANE);
    unsigned short* Wth = wsu + 3*PLANE;
    unsigned short* Wtl = wsu + 3*PLANE + WPLANE;

    hipLaunchKernelGGL(split_k_f16_kernel, dim3(PLANE/1024), dim3(256), 0, stream,
                       Kp, Kh, Kl);
    hipLaunchKernelGGL(transpose_v_f16_kernel, dim3(NB*32*8), dim3(256), 0, stream,
                       Vp, Vt);
    hipLaunchKernelGGL(transpose_split_w_kernel, dim3(64), dim3(256), 0, stream,
                       Wp, Wth, Wtl);
    hipLaunchKernelGGL(attn_kernel, dim3(NB*(NQ/QB)), dim3(512), 0, stream,
                       Qp, Mp, Kh, Kl, Vt, Wth, Wtl, Op);
}

// Round 12
// 367.502 us; speedup vs baseline: 1.2574x; 1.2574x over previous
//
#include <hip/hip_runtime.h>

#define NB 8
#define NQ 2048
#define NK 2048
#define ND 512
#define QB 64
#define KB 256
#define MASK_VALUE (-1e-06f)
#define PLANE  ((size_t)NB * NK * ND)
#define WPLANE ((size_t)ND * ND)

typedef __attribute__((ext_vector_type(4))) float f32x4;
typedef __attribute__((ext_vector_type(8))) __bf16 bf16x8;
typedef __attribute__((ext_vector_type(8))) _Float16 f16x8;
typedef __attribute__((ext_vector_type(4))) _Float16 f16x4;
typedef __attribute__((ext_vector_type(8))) unsigned short u16x8;
typedef __attribute__((ext_vector_type(4))) unsigned int u32x4;

typedef f32x4  __attribute__((may_alias)) f32x4_ma;
typedef bf16x8 __attribute__((may_alias)) bf16x8_ma;
typedef f16x8  __attribute__((may_alias)) f16x8_ma;
typedef f16x4  __attribute__((may_alias)) f16x4_ma;
typedef u32x4  __attribute__((may_alias)) u32x4_ma;

__device__ __forceinline__ unsigned short f2bf(float x){
    union { float f; unsigned u; } v; v.f = x;
    unsigned r = v.u + 0x7fffu + ((v.u >> 16) & 1u);
    return (unsigned short)(r >> 16);
}
__device__ __forceinline__ float bf2f(unsigned short h){
    union { unsigned u; float f; } v; v.u = ((unsigned)h) << 16;
    return v.f;
}

// ---------------- prep 1: K -> hi/lo fp16 planes, layout [b][k][e] ----------------
__global__ __launch_bounds__(256)
void split_k_f16_kernel(const float* __restrict__ K,
                        _Float16* __restrict__ kh,
                        _Float16* __restrict__ kl)
{
    const size_t i = ((size_t)blockIdx.x * 256 + threadIdx.x) * 4;
    const f32x4 v = *(const f32x4_ma*)(K + i);
    f16x4 h, l;
    #pragma unroll
    for (int c = 0; c < 4; ++c){
        h[c] = (_Float16)v[c];
        l[c] = (_Float16)(v[c] - (float)h[c]);
    }
    *(f16x4_ma*)(kh + i) = h;
    *(f16x4_ma*)(kl + i) = l;
}

// -------- prep 2: V -> single fp16 plane TRANSPOSED, layout [b][d][k] --------
__global__ __launch_bounds__(256)
void transpose_v_f16_kernel(const float* __restrict__ V,
                            _Float16* __restrict__ vt)
{
    __shared__ float t[64][68];
    const int tid = threadIdx.x;
    const int bid = blockIdx.x;
    const int dt  = bid & 7;
    const int kt  = (bid >> 3) & 31;
    const int b   = bid >> 8;
    {
        const int rr = tid >> 4;
        const int c4 = (tid & 15) * 4;
        #pragma unroll
        for (int m4 = 0; m4 < 4; ++m4){
            const int kr = rr + m4*16;
            *(f32x4_ma*)&t[kr][c4] =
                *(const f32x4_ma*)&V[((size_t)b*NK + kt*64 + kr)*ND + dt*64 + c4];
        }
    }
    __syncthreads();
    {
        const int dr = tid >> 2;
        const int kc = (tid & 3) * 16;
        f16x8 v0, v1;
        #pragma unroll
        for (int j = 0; j < 8; ++j) v0[j] = (_Float16)t[kc + j][dr];
        #pragma unroll
        for (int j = 0; j < 8; ++j) v1[j] = (_Float16)t[kc + 8 + j][dr];
        const size_t dst = ((size_t)b*ND + dt*64 + dr)*NK + kt*64 + kc;
        *(f16x8_ma*)(vt + dst)     = v0;
        *(f16x8_ma*)(vt + dst + 8) = v1;
    }
}

// -------- prep 3: W -> hi/lo bf16 planes TRANSPOSED, layout [e][d] --------
__global__ __launch_bounds__(256)
void transpose_split_w_kernel(const float* __restrict__ W,
                              unsigned short* __restrict__ wth,
                              unsigned short* __restrict__ wtl)
{
    __shared__ float t[64][68];
    const int tid = threadIdx.x;
    const int et  = blockIdx.x & 7;
    const int dt  = blockIdx.x >> 3;
    {
        const int rr = tid >> 4;
        const int c4 = (tid & 15) * 4;
        #pragma unroll
        for (int m4 = 0; m4 < 4; ++m4){
            const int dr = rr + m4*16;
            *(f32x4_ma*)&t[dr][c4] =
                *(const f32x4_ma*)&W[(size_t)(dt*64 + dr)*ND + et*64 + c4];
        }
    }
    __syncthreads();
    {
        const int er = tid >> 2;
        const int dc = (tid & 3) * 16;
        unsigned short hh[16], ll[16];
        #pragma unroll
        for (int j = 0; j < 16; ++j){
            const float v = t[dc + j][er];
            const unsigned short h = f2bf(v);
            hh[j] = h;
            ll[j] = f2bf(v - bf2f(h));
        }
        u32x4 h0, h1, l0, l1;
        #pragma unroll
        for (int c = 0; c < 4; ++c){
            h0[c] = (unsigned)hh[2*c]   | ((unsigned)hh[2*c+1] << 16);
            h1[c] = (unsigned)hh[8+2*c] | ((unsigned)hh[9+2*c] << 16);
            l0[c] = (unsigned)ll[2*c]   | ((unsigned)ll[2*c+1] << 16);
            l1[c] = (unsigned)ll[8+2*c] | ((unsigned)ll[9+2*c] << 16);
        }
        const size_t dst = (size_t)(et*64 + er)*ND + dt*64 + dc;
        *(u32x4_ma*)(wth + dst)     = h0;
        *(u32x4_ma*)(wth + dst + 8) = h1;
        *(u32x4_ma*)(wtl + dst)     = l0;
        *(u32x4_ma*)(wtl + dst + 8) = l1;
    }
}

// ------ main fused kernel: 16 waves, QB=64, KB=256; QK(t+1) pipelined with PV(t) ------
__global__ __launch_bounds__(1024, 4)
void attn_kernel(const float* __restrict__ Qp, const int* __restrict__ Mp,
                 const _Float16* __restrict__ Kh, const _Float16* __restrict__ Kl,
                 const _Float16* __restrict__ Vt,
                 const unsigned short* __restrict__ Wth, const unsigned short* __restrict__ Wtl,
                 float* __restrict__ Op)
{
    __shared__ _Float16 qw[QB][520];      // 66.6 KB
    __shared__ _Float16 p_b[2][QB][264];  // 67.6 KB (double-buffered)
    __shared__ float wredA[QB][16];       // 4 KB -> 138 KB total, 1 block/CU

    const int tid  = threadIdx.x;
    const int lane = tid & 63;
    const int wv   = tid >> 6;              // wave 0..15
    const int lm   = lane & 15;
    const int lg   = lane >> 4;
    const int b    = blockIdx.x & 7;        // batch -> XCD affinity
    const int q0   = (int)(blockIdx.x >> 3) * QB;

    int mk;
    {   // tolerate int64-encoded masks (values >=1, so odd words all-zero => int64)
        const int odd = Mp[1] | Mp[3] | Mp[5] | Mp[7];
        mk = (odd == 0) ? Mp[2*b] : Mp[b];
    }

    // ===== Phase 1: qw[64][512] = Q_tile @ W via bf16 hi/lo 3-term MFMA =====
    {
        f32x4 acc[4][2];
        #pragma unroll
        for (int m2 = 0; m2 < 4; ++m2)
            #pragma unroll
            for (int n2 = 0; n2 < 2; ++n2) acc[m2][n2] = (f32x4){0.f,0.f,0.f,0.f};

        for (int w = 0; w < 16; ++w){
            bf16x8 aH[4], aL[4];
            #pragma unroll
            for (int m2 = 0; m2 < 4; ++m2){
                const float* qp = Qp + ((size_t)b*NQ + q0 + m2*16 + lm)*ND + w*32 + lg*8;
                const f32x4 qa = *(const f32x4_ma*)qp;
                const f32x4 qb = *(const f32x4_ma*)(qp + 4);
                u16x8 hh, ll;
                #pragma unroll
                for (int c = 0; c < 4; ++c){
                    const unsigned short h = f2bf(qa[c]);
                    hh[c] = h; ll[c] = f2bf(qa[c] - bf2f(h));
                }
                #pragma unroll
                for (int c = 0; c < 4; ++c){
                    const unsigned short h = f2bf(qb[c]);
                    hh[4+c] = h; ll[4+c] = f2bf(qb[c] - bf2f(h));
                }
                aH[m2] = __builtin_bit_cast(bf16x8, hh);
                aL[m2] = __builtin_bit_cast(bf16x8, ll);
            }
            #pragma unroll
            for (int n2 = 0; n2 < 2; ++n2){
                const size_t wrow = (size_t)(wv*32 + n2*16 + lm)*ND + w*32 + lg*8;
                const bf16x8 bh = *(const bf16x8_ma*)(Wth + wrow);
                const bf16x8 bl = *(const bf16x8_ma*)(Wtl + wrow);
                #pragma unroll
                for (int m2 = 0; m2 < 4; ++m2){
                    acc[m2][n2] = __builtin_amdgcn_mfma_f32_16x16x32_bf16(aH[m2], bh, acc[m2][n2], 0,0,0);
                    acc[m2][n2] = __builtin_amdgcn_mfma_f32_16x16x32_bf16(aH[m2], bl, acc[m2][n2], 0,0,0);
                    acc[m2][n2] = __builtin_amdgcn_mfma_f32_16x16x32_bf16(aL[m2], bh, acc[m2][n2], 0,0,0);
                }
            }
        }
        #pragma unroll
        for (int m2 = 0; m2 < 4; ++m2)
            #pragma unroll
            for (int n2 = 0; n2 < 2; ++n2)
                #pragma unroll
                for (int r = 0; r < 4; ++r)
                    qw[m2*16 + lg*4 + r][wv*32 + n2*16 + lm] = (_Float16)acc[m2][n2][r];
    }
    __syncthreads();

    // ===== Phase 2: pipelined flash loop (QK of tile t+1 fused with PV of tile t) =====
    float m_run[4][4];
    #pragma unroll
    for (int m2 = 0; m2 < 4; ++m2)
        #pragma unroll
        for (int r = 0; r < 4; ++r) m_run[m2][r] = -3.0e38f;

    f32x4 o_acc[4][2];
    f32x4 l_acc[4];
    #pragma unroll
    for (int m2 = 0; m2 < 4; ++m2){
        l_acc[m2] = (f32x4){0.f,0.f,0.f,0.f};
        #pragma unroll
        for (int n = 0; n < 2; ++n) o_acc[m2][n] = (f32x4){0.f,0.f,0.f,0.f};
    }

    f16x8 ones;
    #pragma unroll
    for (int j = 0; j < 8; ++j) ones[j] = (_Float16)1.0f;

    const _Float16* khb = Kh + ((size_t)b*NK + wv*16 + lm)*ND;
    const _Float16* klb = Kl + ((size_t)b*NK + wv*16 + lm)*ND;
    const size_t vbase = ((size_t)b*ND + wv*32 + lm)*NK + lg*8;

    float sv[4][4];   // masked scores of the tile being softmaxed (carried across barrier)

    // ---- QK macro body (tile index kt_, results -> sv + wredA publish) ----
#define QK_TILE(kt_)                                                                     \
    {                                                                                    \
        const int k0n = (kt_) * KB;                                                      \
        const size_t koff = (size_t)k0n * ND;                                            \
        f32x4 sacc[4];                                                                   \
        _Pragma("unroll")                                                                \
        for (int m2 = 0; m2 < 4; ++m2) sacc[m2] = (f32x4){0.f,0.f,0.f,0.f};              \
        _Pragma("unroll")                                                                \
        for (int w = 0; w < 16; ++w){                                                    \
            const int eoff = w*32 + lg*8;                                                \
            const f16x8 bh = *(const f16x8_ma*)(khb + koff + eoff);                      \
            const f16x8 bl = *(const f16x8_ma*)(klb + koff + eoff);                      \
            _Pragma("unroll")                                                            \
            for (int m2 = 0; m2 < 4; ++m2){                                              \
                const f16x8 aQ = *(const f16x8_ma*)&qw[m2*16 + lm][eoff];                \
                sacc[m2] = __builtin_amdgcn_mfma_f32_16x16x32_f16(aQ, bh, sacc[m2], 0,0,0);\
                sacc[m2] = __builtin_amdgcn_mfma_f32_16x16x32_f16(aQ, bl, sacc[m2], 0,0,0);\
            }                                                                            \
        }                                                                                \
        const bool inval = (k0n + wv*16 + lm) >= mk;                                     \
        _Pragma("unroll")                                                                \
        for (int m2 = 0; m2 < 4; ++m2)                                                   \
            _Pragma("unroll")                                                            \
            for (int r = 0; r < 4; ++r) sv[m2][r] = inval ? MASK_VALUE : sacc[m2][r];    \
        float pm[4][4];                                                                  \
        _Pragma("unroll")                                                                \
        for (int m2 = 0; m2 < 4; ++m2)                                                   \
            _Pragma("unroll")                                                            \
            for (int r = 0; r < 4; ++r) pm[m2][r] = sv[m2][r];                           \
        _Pragma("unroll")                                                                \
        for (int off = 1; off < 16; off <<= 1)                                           \
            _Pragma("unroll")                                                            \
            for (int m2 = 0; m2 < 4; ++m2)                                               \
                _Pragma("unroll")                                                        \
                for (int r = 0; r < 4; ++r)                                              \
                    pm[m2][r] = fmaxf(pm[m2][r], __shfl_xor(pm[m2][r], off, 64));        \
        if (lm == 0){                                                                    \
            _Pragma("unroll")                                                            \
            for (int m2 = 0; m2 < 4; ++m2)                                               \
                _Pragma("unroll")                                                        \
                for (int r = 0; r < 4; ++r) wredA[m2*16 + lg*4 + r][wv] = pm[m2][r];     \
        }                                                                                \
    }

    // ---- softmax macro (consumes sv + wredA, writes p_b[buf_], rescales o/l) ----
#define SOFTMAX_TILE(buf_)                                                               \
    {                                                                                    \
        _Pragma("unroll")                                                                \
        for (int m2 = 0; m2 < 4; ++m2)                                                   \
            _Pragma("unroll")                                                            \
            for (int r = 0; r < 4; ++r){                                                 \
                const int row = m2*16 + lg*4 + r;                                        \
                const f32x4 g0 = *(const f32x4_ma*)&wredA[row][0];                       \
                const f32x4 g1 = *(const f32x4_ma*)&wredA[row][4];                       \
                const f32x4 g2 = *(const f32x4_ma*)&wredA[row][8];                       \
                const f32x4 g3 = *(const f32x4_ma*)&wredA[row][12];                      \
                float gm = fmaxf(fmaxf(fmaxf(g0[0],g0[1]),fmaxf(g0[2],g0[3])),           \
                                 fmaxf(fmaxf(g1[0],g1[1]),fmaxf(g1[2],g1[3])));          \
                gm = fmaxf(gm, fmaxf(fmaxf(fmaxf(g2[0],g2[1]),fmaxf(g2[2],g2[3])),       \
                                     fmaxf(fmaxf(g3[0],g3[1]),fmaxf(g3[2],g3[3]))));     \
                if (gm > m_run[m2][r]){                                                  \
                    const float fsc = __expf(m_run[m2][r] - gm);                         \
                    m_run[m2][r] = gm;                                                   \
                    o_acc[m2][0][r] *= fsc;                                              \
                    o_acc[m2][1][r] *= fsc;                                              \
                    l_acc[m2][r]    *= fsc;                                              \
                }                                                                        \
                p_b[buf_][row][wv*16 + lm] = (_Float16)__expf(sv[m2][r] - m_run[m2][r]); \
            }                                                                            \
    }

    // ---- prologue: QK(0) -> softmax(0) -> p_b[0] ----
    QK_TILE(0);
    __syncthreads();
    SOFTMAX_TILE(0);
    __syncthreads();

    for (int kt = 0; kt < 8; ++kt){
        const int cur = kt & 1;
        // fused region: QK(kt+1) first (K loads issue early, latency hidden by PV MFMAs)
        if (kt < 7){
            QK_TILE(kt + 1);
        }
        // PV(kt) from p_b[cur] + V(kt)
        {
            const int k0 = kt * KB;
            #pragma unroll
            for (int kb = 0; kb < 8; ++kb){
                f16x8 pa[4];
                #pragma unroll
                for (int m2 = 0; m2 < 4; ++m2)
                    pa[m2] = *(const f16x8_ma*)&p_b[cur][m2*16 + lm][kb*32 + lg*8];
                #pragma unroll
                for (int n = 0; n < 2; ++n){
                    const f16x8 vv = *(const f16x8_ma*)(Vt + vbase + (size_t)n*16*NK + k0 + kb*32);
                    #pragma unroll
                    for (int m2 = 0; m2 < 4; ++m2)
                        o_acc[m2][n] = __builtin_amdgcn_mfma_f32_16x16x32_f16(pa[m2], vv, o_acc[m2][n], 0,0,0);
                }
                #pragma unroll
                for (int m2 = 0; m2 < 4; ++m2)
                    l_acc[m2] = __builtin_amdgcn_mfma_f32_16x16x32_f16(pa[m2], ones, l_acc[m2], 0,0,0);
            }
        }
        __syncthreads();                 // publish(kt+1) visible; PV(kt) done with p_b[cur]
        if (kt < 7){
            SOFTMAX_TILE(cur ^ 1);       // rescale o/l by fsc(kt+1), write p_b[cur^1]
        }
        __syncthreads();                 // p_b[cur^1] visible for next PV
    }
#undef QK_TILE
#undef SOFTMAX_TILE

    // ===== epilogue: normalize with the consistent denominator =====
    #pragma unroll
    for (int m2 = 0; m2 < 4; ++m2){
        float li[4];
        #pragma unroll
        for (int r = 0; r < 4; ++r) li[r] = 1.f / l_acc[m2][r];
        #pragma unroll
        for (int n = 0; n < 2; ++n)
            #pragma unroll
            for (int r = 0; r < 4; ++r)
                Op[((size_t)b*NQ + q0 + m2*16 + lg*4 + r)*ND + wv*32 + n*16 + lm]
                    = o_acc[m2][n][r] * li[r];
    }
}

extern "C" void kernel_launch(void* const* d_in, const int* in_sizes, int n_in,
                              void* d_out, int out_size, void* d_ws, size_t ws_size,
                              hipStream_t stream)
{
    (void)in_sizes; (void)n_in; (void)out_size; (void)ws_size;
    const float* Qp = (const float*)d_in[0];
    const float* Kp = (const float*)d_in[1];
    const float* Vp = (const float*)d_in[2];
    const float* Wp = (const float*)d_in[3];
    const int*   Mp = (const int*)  d_in[4];
    float* Op = (float*)d_out;

    unsigned short* wsu = (unsigned short*)d_ws;
    _Float16*       Kh  = (_Float16*)wsu;
    _Float16*       Kl  = (_Float16*)(wsu + PLANE);
    _Float16*       Vt  = (_Float16*)(wsu + 2*PLANE);
    unsigned short* Wth = wsu + 3*PLANE;
    unsigned short* Wtl = wsu + 3*PLANE + WPLANE;

    hipLaunchKernelGGL(split_k_f16_kernel, dim3(PLANE/1024), dim3(256), 0, stream,
                       Kp, Kh, Kl);
    hipLaunchKernelGGL(transpose_v_f16_kernel, dim3(NB*32*8), dim3(256), 0, stream,
                       Vp, Vt);
    hipLaunchKernelGGL(transpose_split_w_kernel, dim3(64), dim3(256), 0, stream,
                       Wp, Wth, Wtl);
    hipLaunchKernelGGL(attn_kernel, dim3(NB*(NQ/QB)), dim3(1024), 0, stream,
                       Qp, Mp, Kh, Kl, Vt, Wth, Wtl, Op);
}

// Round 13
// 301.198 us; speedup vs baseline: 1.5342x; 1.2201x over previous
//
#include <hip/hip_runtime.h>

#define NB 8
#define NQ 2048
#define NK 2048
#define ND 512
#define QB 64
#define KB 256
#define MASK_VALUE (-1e-06f)
#define PLANE  ((size_t)NB * NK * ND)
#define WPLANE ((size_t)ND * ND)

typedef __attribute__((ext_vector_type(4))) float f32x4;
typedef __attribute__((ext_vector_type(8))) __bf16 bf16x8;
typedef __attribute__((ext_vector_type(8))) _Float16 f16x8;
typedef __attribute__((ext_vector_type(4))) _Float16 f16x4;
typedef __attribute__((ext_vector_type(8))) unsigned short u16x8;
typedef __attribute__((ext_vector_type(4))) unsigned int u32x4;

typedef f32x4  __attribute__((may_alias)) f32x4_ma;
typedef bf16x8 __attribute__((may_alias)) bf16x8_ma;
typedef f16x8  __attribute__((may_alias)) f16x8_ma;
typedef f16x4  __attribute__((may_alias)) f16x4_ma;
typedef u32x4  __attribute__((may_alias)) u32x4_ma;

__device__ __forceinline__ unsigned short f2bf(float x){
    union { float f; unsigned u; } v; v.f = x;
    unsigned r = v.u + 0x7fffu + ((v.u >> 16) & 1u);
    return (unsigned short)(r >> 16);
}
__device__ __forceinline__ float bf2f(unsigned short h){
    union { unsigned u; float f; } v; v.u = ((unsigned)h) << 16;
    return v.f;
}

// ---------------- prep 1: K -> SINGLE fp16 plane, layout [b][k][e] ----------------
// fp16 has 11 mantissa bits: score error sigma ~ 0.004 (Lipschitz-bounded output
// impact ~0.01) -> the hi/lo split is unnecessary. Halves QK MFMAs AND K traffic;
// per-XCD working set drops to K(2MB)+V(2MB) = 4MB = exactly one XCD L2.
__global__ __launch_bounds__(256)
void conv_k_f16_kernel(const float* __restrict__ K,
                       _Float16* __restrict__ kf)
{
    const size_t i = ((size_t)blockIdx.x * 256 + threadIdx.x) * 4;
    const f32x4 v = *(const f32x4_ma*)(K + i);
    f16x4 h;
    #pragma unroll
    for (int c = 0; c < 4; ++c) h[c] = (_Float16)v[c];
    *(f16x4_ma*)(kf + i) = h;
}

// -------- prep 2: V -> single fp16 plane TRANSPOSED, layout [b][d][k] --------
__global__ __launch_bounds__(256)
void transpose_v_f16_kernel(const float* __restrict__ V,
                            _Float16* __restrict__ vt)
{
    __shared__ float t[64][68];
    const int tid = threadIdx.x;
    const int bid = blockIdx.x;
    const int dt  = bid & 7;
    const int kt  = (bid >> 3) & 31;
    const int b   = bid >> 8;
    {
        const int rr = tid >> 4;
        const int c4 = (tid & 15) * 4;
        #pragma unroll
        for (int m4 = 0; m4 < 4; ++m4){
            const int kr = rr + m4*16;
            *(f32x4_ma*)&t[kr][c4] =
                *(const f32x4_ma*)&V[((size_t)b*NK + kt*64 + kr)*ND + dt*64 + c4];
        }
    }
    __syncthreads();
    {
        const int dr = tid >> 2;
        const int kc = (tid & 3) * 16;
        f16x8 v0, v1;
        #pragma unroll
        for (int j = 0; j < 8; ++j) v0[j] = (_Float16)t[kc + j][dr];
        #pragma unroll
        for (int j = 0; j < 8; ++j) v1[j] = (_Float16)t[kc + 8 + j][dr];
        const size_t dst = ((size_t)b*ND + dt*64 + dr)*NK + kt*64 + kc;
        *(f16x8_ma*)(vt + dst)     = v0;
        *(f16x8_ma*)(vt + dst + 8) = v1;
    }
}

// -------- prep 3: W -> hi/lo bf16 planes TRANSPOSED, layout [e][d] --------
__global__ __launch_bounds__(256)
void transpose_split_w_kernel(const float* __restrict__ W,
                              unsigned short* __restrict__ wth,
                              unsigned short* __restrict__ wtl)
{
    __shared__ float t[64][68];
    const int tid = threadIdx.x;
    const int et  = blockIdx.x & 7;
    const int dt  = blockIdx.x >> 3;
    {
        const int rr = tid >> 4;
        const int c4 = (tid & 15) * 4;
        #pragma unroll
        for (int m4 = 0; m4 < 4; ++m4){
            const int dr = rr + m4*16;
            *(f32x4_ma*)&t[dr][c4] =
                *(const f32x4_ma*)&W[(size_t)(dt*64 + dr)*ND + et*64 + c4];
        }
    }
    __syncthreads();
    {
        const int er = tid >> 2;
        const int dc = (tid & 3) * 16;
        unsigned short hh[16], ll[16];
        #pragma unroll
        for (int j = 0; j < 16; ++j){
            const float v = t[dc + j][er];
            const unsigned short h = f2bf(v);
            hh[j] = h;
            ll[j] = f2bf(v - bf2f(h));
        }
        u32x4 h0, h1, l0, l1;
        #pragma unroll
        for (int c = 0; c < 4; ++c){
            h0[c] = (unsigned)hh[2*c]   | ((unsigned)hh[2*c+1] << 16);
            h1[c] = (unsigned)hh[8+2*c] | ((unsigned)hh[9+2*c] << 16);
            l0[c] = (unsigned)ll[2*c]   | ((unsigned)ll[2*c+1] << 16);
            l1[c] = (unsigned)ll[8+2*c] | ((unsigned)ll[9+2*c] << 16);
        }
        const size_t dst = (size_t)(et*64 + er)*ND + dt*64 + dc;
        *(u32x4_ma*)(wth + dst)     = h0;
        *(u32x4_ma*)(wth + dst + 8) = h1;
        *(u32x4_ma*)(wtl + dst)     = l0;
        *(u32x4_ma*)(wtl + dst + 8) = l1;
    }
}

// ----- main fused kernel: r9 structure, single-fp16-K QK, K loads batched 4-ahead -----
__global__ __launch_bounds__(1024, 4)
void attn_kernel(const float* __restrict__ Qp, const int* __restrict__ Mp,
                 const _Float16* __restrict__ Kf,
                 const _Float16* __restrict__ Vt,
                 const unsigned short* __restrict__ Wth, const unsigned short* __restrict__ Wtl,
                 float* __restrict__ Op)
{
    __shared__ _Float16 qw[QB][520];
    __shared__ _Float16 p_b[QB][264];
    __shared__ float wredA[QB][16];     // ~104 KB total -> 1 block/CU (16 waves)

    const int tid  = threadIdx.x;
    const int lane = tid & 63;
    const int wv   = tid >> 6;              // wave 0..15
    const int lm   = lane & 15;
    const int lg   = lane >> 4;
    const int b    = blockIdx.x & 7;        // batch -> XCD affinity
    const int q0   = (int)(blockIdx.x >> 3) * QB;

    int mk;
    {   // tolerate int64-encoded masks (values >=1, so odd words all-zero => int64)
        const int odd = Mp[1] | Mp[3] | Mp[5] | Mp[7];
        mk = (odd == 0) ? Mp[2*b] : Mp[b];
    }

    // ===== Phase 1: qw[64][512] = Q_tile @ W via bf16 hi/lo 3-term MFMA =====
    {
        f32x4 acc[4][2];
        #pragma unroll
        for (int m2 = 0; m2 < 4; ++m2)
            #pragma unroll
            for (int n2 = 0; n2 < 2; ++n2) acc[m2][n2] = (f32x4){0.f,0.f,0.f,0.f};

        for (int w = 0; w < 16; ++w){
            bf16x8 aH[4], aL[4];
            #pragma unroll
            for (int m2 = 0; m2 < 4; ++m2){
                const float* qp = Qp + ((size_t)b*NQ + q0 + m2*16 + lm)*ND + w*32 + lg*8;
                const f32x4 qa = *(const f32x4_ma*)qp;
                const f32x4 qb = *(const f32x4_ma*)(qp + 4);
                u16x8 hh, ll;
                #pragma unroll
                for (int c = 0; c < 4; ++c){
                    const unsigned short h = f2bf(qa[c]);
                    hh[c] = h; ll[c] = f2bf(qa[c] - bf2f(h));
                }
                #pragma unroll
                for (int c = 0; c < 4; ++c){
                    const unsigned short h = f2bf(qb[c]);
                    hh[4+c] = h; ll[4+c] = f2bf(qb[c] - bf2f(h));
                }
                aH[m2] = __builtin_bit_cast(bf16x8, hh);
                aL[m2] = __builtin_bit_cast(bf16x8, ll);
            }
            #pragma unroll
            for (int n2 = 0; n2 < 2; ++n2){
                const size_t wrow = (size_t)(wv*32 + n2*16 + lm)*ND + w*32 + lg*8;
                const bf16x8 bh = *(const bf16x8_ma*)(Wth + wrow);
                const bf16x8 bl = *(const bf16x8_ma*)(Wtl + wrow);
                #pragma unroll
                for (int m2 = 0; m2 < 4; ++m2){
                    acc[m2][n2] = __builtin_amdgcn_mfma_f32_16x16x32_bf16(aH[m2], bh, acc[m2][n2], 0,0,0);
                    acc[m2][n2] = __builtin_amdgcn_mfma_f32_16x16x32_bf16(aH[m2], bl, acc[m2][n2], 0,0,0);
                    acc[m2][n2] = __builtin_amdgcn_mfma_f32_16x16x32_bf16(aL[m2], bh, acc[m2][n2], 0,0,0);
                }
            }
        }
        #pragma unroll
        for (int m2 = 0; m2 < 4; ++m2)
            #pragma unroll
            for (int n2 = 0; n2 < 2; ++n2)
                #pragma unroll
                for (int r = 0; r < 4; ++r)
                    qw[m2*16 + lg*4 + r][wv*32 + n2*16 + lm] = (_Float16)acc[m2][n2][r];
    }
    __syncthreads();

    // ===== Phase 2: flash loop over 8 tiles of 256 keys =====
    float m_run[4][4];
    #pragma unroll
    for (int m2 = 0; m2 < 4; ++m2)
        #pragma unroll
        for (int r = 0; r < 4; ++r) m_run[m2][r] = -3.0e38f;

    f32x4 o_acc[4][2];
    f32x4 l_acc[4];
    #pragma unroll
    for (int m2 = 0; m2 < 4; ++m2){
        l_acc[m2] = (f32x4){0.f,0.f,0.f,0.f};
        #pragma unroll
        for (int n = 0; n < 2; ++n) o_acc[m2][n] = (f32x4){0.f,0.f,0.f,0.f};
    }

    f16x8 ones;
    #pragma unroll
    for (int j = 0; j < 8; ++j) ones[j] = (_Float16)1.0f;

    const _Float16* kfb = Kf + ((size_t)b*NK + wv*16 + lm)*ND;
    const size_t vbase = ((size_t)b*ND + wv*32 + lm)*NK + lg*8;

    for (int kt = 0; kt < 8; ++kt){
        const int k0 = kt * KB;
        const size_t koff = (size_t)k0 * ND;

        // ---- QK^T (single-term fp16): K loads batched 4 windows ahead ----
        f32x4 sacc[4];
        #pragma unroll
        for (int m2 = 0; m2 < 4; ++m2) sacc[m2] = (f32x4){0.f,0.f,0.f,0.f};
        #pragma unroll
        for (int w4 = 0; w4 < 4; ++w4){
            f16x8 bk[4];
            #pragma unroll
            for (int j = 0; j < 4; ++j)
                bk[j] = *(const f16x8_ma*)(kfb + koff + (w4*4 + j)*32 + lg*8);
            #pragma unroll
            for (int j = 0; j < 4; ++j){
                const int eoff = (w4*4 + j)*32 + lg*8;
                #pragma unroll
                for (int m2 = 0; m2 < 4; ++m2){
                    const f16x8 aQ = *(const f16x8_ma*)&qw[m2*16 + lm][eoff];
                    sacc[m2] = __builtin_amdgcn_mfma_f32_16x16x32_f16(aQ, bk[j], sacc[m2], 0,0,0);
                }
            }
        }

        // ---- faithful mask (lane-local key: k0 + wv*16 + lm) ----
        const bool inval = (k0 + wv*16 + lm) >= mk;
        float sv[4][4];
        #pragma unroll
        for (int m2 = 0; m2 < 4; ++m2)
            #pragma unroll
            for (int r = 0; r < 4; ++r) sv[m2][r] = inval ? MASK_VALUE : sacc[m2][r];

        // ---- per-wave row max over its 16 keys, publish ----
        float pm[4][4];
        #pragma unroll
        for (int m2 = 0; m2 < 4; ++m2)
            #pragma unroll
            for (int r = 0; r < 4; ++r) pm[m2][r] = sv[m2][r];
        #pragma unroll
        for (int off = 1; off < 16; off <<= 1)
            #pragma unroll
            for (int m2 = 0; m2 < 4; ++m2)
                #pragma unroll
                for (int r = 0; r < 4; ++r)
                    pm[m2][r] = fmaxf(pm[m2][r], __shfl_xor(pm[m2][r], off, 64));
        if (lm == 0){
            #pragma unroll
            for (int m2 = 0; m2 < 4; ++m2)
                #pragma unroll
                for (int r = 0; r < 4; ++r) wredA[m2*16 + lg*4 + r][wv] = pm[m2][r];
        }
        __syncthreads();

        // ---- mnew + exact defer-max rescale + p -> fp16 LDS ----
        #pragma unroll
        for (int m2 = 0; m2 < 4; ++m2)
            #pragma unroll
            for (int r = 0; r < 4; ++r){
                const int row = m2*16 + lg*4 + r;
                const f32x4 g0 = *(const f32x4_ma*)&wredA[row][0];
                const f32x4 g1 = *(const f32x4_ma*)&wredA[row][4];
                const f32x4 g2 = *(const f32x4_ma*)&wredA[row][8];
                const f32x4 g3 = *(const f32x4_ma*)&wredA[row][12];
                float gm = fmaxf(fmaxf(fmaxf(g0[0],g0[1]),fmaxf(g0[2],g0[3])),
                                 fmaxf(fmaxf(g1[0],g1[1]),fmaxf(g1[2],g1[3])));
                gm = fmaxf(gm, fmaxf(fmaxf(fmaxf(g2[0],g2[1]),fmaxf(g2[2],g2[3])),
                                     fmaxf(fmaxf(g3[0],g3[1]),fmaxf(g3[2],g3[3]))));
                if (gm > m_run[m2][r]){          // exact skip: fsc==1 when gm<=m_run
                    const float fsc = __expf(m_run[m2][r] - gm);
                    m_run[m2][r] = gm;
                    o_acc[m2][0][r] *= fsc;
                    o_acc[m2][1][r] *= fsc;
                    l_acc[m2][r]    *= fsc;
                }
                p_b[row][wv*16 + lm] = (_Float16)__expf(sv[m2][r] - m_run[m2][r]);
            }
        __syncthreads();

        // ---- PV + ones-MFMA denominator ----
        #pragma unroll
        for (int kb = 0; kb < 8; ++kb){
            f16x8 pa[4];
            #pragma unroll
            for (int m2 = 0; m2 < 4; ++m2)
                pa[m2] = *(const f16x8_ma*)&p_b[m2*16 + lm][kb*32 + lg*8];
            #pragma unroll
            for (int n = 0; n < 2; ++n){
                const f16x8 vv = *(const f16x8_ma*)(Vt + vbase + (size_t)n*16*NK + k0 + kb*32);
                #pragma unroll
                for (int m2 = 0; m2 < 4; ++m2)
                    o_acc[m2][n] = __builtin_amdgcn_mfma_f32_16x16x32_f16(pa[m2], vv, o_acc[m2][n], 0,0,0);
            }
            #pragma unroll
            for (int m2 = 0; m2 < 4; ++m2)
                l_acc[m2] = __builtin_amdgcn_mfma_f32_16x16x32_f16(pa[m2], ones, l_acc[m2], 0,0,0);
        }
    }

    // ===== epilogue: normalize with the consistent denominator =====
    #pragma unroll
    for (int m2 = 0; m2 < 4; ++m2){
        float li[4];
        #pragma unroll
        for (int r = 0; r < 4; ++r) li[r] = 1.f / l_acc[m2][r];
        #pragma unroll
        for (int n = 0; n < 2; ++n)
            #pragma unroll
            for (int r = 0; r < 4; ++r)
                Op[((size_t)b*NQ + q0 + m2*16 + lg*4 + r)*ND + wv*32 + n*16 + lm]
                    = o_acc[m2][n][r] * li[r];
    }
}

extern "C" void kernel_launch(void* const* d_in, const int* in_sizes, int n_in,
                              void* d_out, int out_size, void* d_ws, size_t ws_size,
                              hipStream_t stream)
{
    (void)in_sizes; (void)n_in; (void)out_size; (void)ws_size;
    const float* Qp = (const float*)d_in[0];
    const float* Kp = (const float*)d_in[1];
    const float* Vp = (const float*)d_in[2];
    const float* Wp = (const float*)d_in[3];
    const int*   Mp = (const int*)  d_in[4];
    float* Op = (float*)d_out;

    unsigned short* wsu = (unsigned short*)d_ws;   // 34.6 MB total
    _Float16*       Kf  = (_Float16*)wsu;
    _Float16*       Vt  = (_Float16*)(wsu + PLANE);
    unsigned short* Wth = wsu + 2*PLANE;
    unsigned short* Wtl = wsu + 2*PLANE + WPLANE;

    hipLaunchKernelGGL(conv_k_f16_kernel, dim3(PLANE/1024), dim3(256), 0, stream,
                       Kp, Kf);
    hipLaunchKernelGGL(transpose_v_f16_kernel, dim3(NB*32*8), dim3(256), 0, stream,
                       Vp, Vt);
    hipLaunchKernelGGL(transpose_split_w_kernel, dim3(64), dim3(256), 0, stream,
                       Wp, Wth, Wtl);
    hipLaunchKernelGGL(attn_kernel, dim3(NB*(NQ/QB)), dim3(1024), 0, stream,
                       Qp, Mp, Kf, Vt, Wth, Wtl, Op);
}

// Round 14
// 272.244 us; speedup vs baseline: 1.6974x; 1.1064x over previous
//
#include <hip/hip_runtime.h>

#define NB 8
#define NQ 2048
#define NK 2048
#define ND 512
#define QB 64
#define KB 512
#define MASK_VALUE (-1e-06f)
#define PLANE  ((size_t)NB * NK * ND)
#define WPLANE ((size_t)ND * ND)

typedef __attribute__((ext_vector_type(4))) float f32x4;
typedef __attribute__((ext_vector_type(8))) __bf16 bf16x8;
typedef __attribute__((ext_vector_type(8))) _Float16 f16x8;
typedef __attribute__((ext_vector_type(4))) _Float16 f16x4;
typedef __attribute__((ext_vector_type(8))) unsigned short u16x8;
typedef __attribute__((ext_vector_type(4))) unsigned int u32x4;

typedef f32x4  __attribute__((may_alias)) f32x4_ma;
typedef bf16x8 __attribute__((may_alias)) bf16x8_ma;
typedef f16x8  __attribute__((may_alias)) f16x8_ma;
typedef f16x4  __attribute__((may_alias)) f16x4_ma;
typedef u32x4  __attribute__((may_alias)) u32x4_ma;

__device__ __forceinline__ unsigned short f2bf(float x){
    union { float f; unsigned u; } v; v.f = x;
    unsigned r = v.u + 0x7fffu + ((v.u >> 16) & 1u);
    return (unsigned short)(r >> 16);
}
__device__ __forceinline__ float bf2f(unsigned short h){
    union { unsigned u; float f; } v; v.u = ((unsigned)h) << 16;
    return v.f;
}

// ---------------- prep 1: K -> SINGLE fp16 plane, layout [b][k][e] ----------------
__global__ __launch_bounds__(256)
void conv_k_f16_kernel(const float* __restrict__ K,
                       _Float16* __restrict__ kf)
{
    const size_t i = ((size_t)blockIdx.x * 256 + threadIdx.x) * 4;
    const f32x4 v = *(const f32x4_ma*)(K + i);
    f16x4 h;
    #pragma unroll
    for (int c = 0; c < 4; ++c) h[c] = (_Float16)v[c];
    *(f16x4_ma*)(kf + i) = h;
}

// -------- prep 2: V -> single fp16 plane TRANSPOSED, layout [b][d][k] --------
__global__ __launch_bounds__(256)
void transpose_v_f16_kernel(const float* __restrict__ V,
                            _Float16* __restrict__ vt)
{
    __shared__ float t[64][68];
    const int tid = threadIdx.x;
    const int bid = blockIdx.x;
    const int dt  = bid & 7;
    const int kt  = (bid >> 3) & 31;
    const int b   = bid >> 8;
    {
        const int rr = tid >> 4;
        const int c4 = (tid & 15) * 4;
        #pragma unroll
        for (int m4 = 0; m4 < 4; ++m4){
            const int kr = rr + m4*16;
            *(f32x4_ma*)&t[kr][c4] =
                *(const f32x4_ma*)&V[((size_t)b*NK + kt*64 + kr)*ND + dt*64 + c4];
        }
    }
    __syncthreads();
    {
        const int dr = tid >> 2;
        const int kc = (tid & 3) * 16;
        f16x8 v0, v1;
        #pragma unroll
        for (int j = 0; j < 8; ++j) v0[j] = (_Float16)t[kc + j][dr];
        #pragma unroll
        for (int j = 0; j < 8; ++j) v1[j] = (_Float16)t[kc + 8 + j][dr];
        const size_t dst = ((size_t)b*ND + dt*64 + dr)*NK + kt*64 + kc;
        *(f16x8_ma*)(vt + dst)     = v0;
        *(f16x8_ma*)(vt + dst + 8) = v1;
    }
}

// -------- prep 3: W -> hi/lo bf16 planes TRANSPOSED, layout [e][d] --------
__global__ __launch_bounds__(256)
void transpose_split_w_kernel(const float* __restrict__ W,
                              unsigned short* __restrict__ wth,
                              unsigned short* __restrict__ wtl)
{
    __shared__ float t[64][68];
    const int tid = threadIdx.x;
    const int et  = blockIdx.x & 7;
    const int dt  = blockIdx.x >> 3;
    {
        const int rr = tid >> 4;
        const int c4 = (tid & 15) * 4;
        #pragma unroll
        for (int m4 = 0; m4 < 4; ++m4){
            const int dr = rr + m4*16;
            *(f32x4_ma*)&t[dr][c4] =
                *(const f32x4_ma*)&W[(size_t)(dt*64 + dr)*ND + et*64 + c4];
        }
    }
    __syncthreads();
    {
        const int er = tid >> 2;
        const int dc = (tid & 3) * 16;
        unsigned short hh[16], ll[16];
        #pragma unroll
        for (int j = 0; j < 16; ++j){
            const float v = t[dc + j][er];
            const unsigned short h = f2bf(v);
            hh[j] = h;
            ll[j] = f2bf(v - bf2f(h));
        }
        u32x4 h0, h1, l0, l1;
        #pragma unroll
        for (int c = 0; c < 4; ++c){
            h0[c] = (unsigned)hh[2*c]   | ((unsigned)hh[2*c+1] << 16);
            h1[c] = (unsigned)hh[8+2*c] | ((unsigned)hh[9+2*c] << 16);
            l0[c] = (unsigned)ll[2*c]   | ((unsigned)ll[2*c+1] << 16);
            l1[c] = (unsigned)ll[8+2*c] | ((unsigned)ll[9+2*c] << 16);
        }
        const size_t dst = (size_t)(et*64 + er)*ND + dt*64 + dc;
        *(u32x4_ma*)(wth + dst)     = h0;
        *(u32x4_ma*)(wth + dst + 8) = h1;
        *(u32x4_ma*)(wtl + dst)     = l0;
        *(u32x4_ma*)(wtl + dst + 8) = l1;
    }
}

// ----- main fused kernel: KB=512 (wave owns 2x16 keys), 4 softmax phases -----
__global__ __launch_bounds__(1024, 4)
void attn_kernel(const float* __restrict__ Qp, const int* __restrict__ Mp,
                 const _Float16* __restrict__ Kf,
                 const _Float16* __restrict__ Vt,
                 const unsigned short* __restrict__ Wth, const unsigned short* __restrict__ Wtl,
                 float* __restrict__ Op)
{
    __shared__ _Float16 qw[QB][520];    // 66.6 KB
    __shared__ _Float16 p_b[QB][520];   // 66.6 KB (512 cols + pad)
    __shared__ float wredA[QB][16];     // 4 KB -> 137 KB total, 1 block/CU

    const int tid  = threadIdx.x;
    const int lane = tid & 63;
    const int wv   = tid >> 6;              // wave 0..15
    const int lm   = lane & 15;
    const int lg   = lane >> 4;
    const int b    = blockIdx.x & 7;        // batch -> XCD affinity
    const int q0   = (int)(blockIdx.x >> 3) * QB;

    int mk;
    {   // tolerate int64-encoded masks (values >=1, so odd words all-zero => int64)
        const int odd = Mp[1] | Mp[3] | Mp[5] | Mp[7];
        mk = (odd == 0) ? Mp[2*b] : Mp[b];
    }

    // ===== Phase 1: qw[64][512] = Q_tile @ W via bf16 hi/lo 3-term MFMA =====
    {
        f32x4 acc[4][2];
        #pragma unroll
        for (int m2 = 0; m2 < 4; ++m2)
            #pragma unroll
            for (int n2 = 0; n2 < 2; ++n2) acc[m2][n2] = (f32x4){0.f,0.f,0.f,0.f};

        for (int w = 0; w < 16; ++w){
            bf16x8 aH[4], aL[4];
            #pragma unroll
            for (int m2 = 0; m2 < 4; ++m2){
                const float* qp = Qp + ((size_t)b*NQ + q0 + m2*16 + lm)*ND + w*32 + lg*8;
                const f32x4 qa = *(const f32x4_ma*)qp;
                const f32x4 qb = *(const f32x4_ma*)(qp + 4);
                u16x8 hh, ll;
                #pragma unroll
                for (int c = 0; c < 4; ++c){
                    const unsigned short h = f2bf(qa[c]);
                    hh[c] = h; ll[c] = f2bf(qa[c] - bf2f(h));
                }
                #pragma unroll
                for (int c = 0; c < 4; ++c){
                    const unsigned short h = f2bf(qb[c]);
                    hh[4+c] = h; ll[4+c] = f2bf(qb[c] - bf2f(h));
                }
                aH[m2] = __builtin_bit_cast(bf16x8, hh);
                aL[m2] = __builtin_bit_cast(bf16x8, ll);
            }
            #pragma unroll
            for (int n2 = 0; n2 < 2; ++n2){
                const size_t wrow = (size_t)(wv*32 + n2*16 + lm)*ND + w*32 + lg*8;
                const bf16x8 bh = *(const bf16x8_ma*)(Wth + wrow);
                const bf16x8 bl = *(const bf16x8_ma*)(Wtl + wrow);
                #pragma unroll
                for (int m2 = 0; m2 < 4; ++m2){
                    acc[m2][n2] = __builtin_amdgcn_mfma_f32_16x16x32_bf16(aH[m2], bh, acc[m2][n2], 0,0,0);
                    acc[m2][n2] = __builtin_amdgcn_mfma_f32_16x16x32_bf16(aH[m2], bl, acc[m2][n2], 0,0,0);
                    acc[m2][n2] = __builtin_amdgcn_mfma_f32_16x16x32_bf16(aL[m2], bh, acc[m2][n2], 0,0,0);
                }
            }
        }
        #pragma unroll
        for (int m2 = 0; m2 < 4; ++m2)
            #pragma unroll
            for (int n2 = 0; n2 < 2; ++n2)
                #pragma unroll
                for (int r = 0; r < 4; ++r)
                    qw[m2*16 + lg*4 + r][wv*32 + n2*16 + lm] = (_Float16)acc[m2][n2][r];
    }
    __syncthreads();

    // ===== Phase 2: flash loop over 4 tiles of 512 keys =====
    float m_run[4][4];
    #pragma unroll
    for (int m2 = 0; m2 < 4; ++m2)
        #pragma unroll
        for (int r = 0; r < 4; ++r) m_run[m2][r] = -3.0e38f;

    f32x4 o_acc[4][2];
    f32x4 l_acc[4];
    #pragma unroll
    for (int m2 = 0; m2 < 4; ++m2){
        l_acc[m2] = (f32x4){0.f,0.f,0.f,0.f};
        #pragma unroll
        for (int n = 0; n < 2; ++n) o_acc[m2][n] = (f32x4){0.f,0.f,0.f,0.f};
    }

    f16x8 ones;
    #pragma unroll
    for (int j = 0; j < 8; ++j) ones[j] = (_Float16)1.0f;

    // wave owns keys {wv*16+lm, 256+wv*16+lm} within each 512-key tile
    const _Float16* kfb = Kf + ((size_t)b*NK + wv*16 + lm)*ND;
    const size_t vbase = ((size_t)b*ND + wv*32 + lm)*NK + lg*8;

    for (int kt = 0; kt < NK/KB; ++kt){
        const int k0 = kt * KB;
        const size_t koff = (size_t)k0 * ND;

        // ---- QK^T (fp16): same qw A-frags serve BOTH key halves (halved LDS traffic) ----
        f32x4 sacc[2][4];
        #pragma unroll
        for (int h = 0; h < 2; ++h)
            #pragma unroll
            for (int m2 = 0; m2 < 4; ++m2) sacc[h][m2] = (f32x4){0.f,0.f,0.f,0.f};
        #pragma unroll
        for (int w2 = 0; w2 < 8; ++w2){
            f16x8 bk[2][2];   // [j window][h half]
            #pragma unroll
            for (int j = 0; j < 2; ++j)
                #pragma unroll
                for (int h = 0; h < 2; ++h)
                    bk[j][h] = *(const f16x8_ma*)(kfb + koff + (size_t)h*256*ND + (w2*2 + j)*32 + lg*8);
            #pragma unroll
            for (int j = 0; j < 2; ++j){
                const int eoff = (w2*2 + j)*32 + lg*8;
                #pragma unroll
                for (int m2 = 0; m2 < 4; ++m2){
                    const f16x8 aQ = *(const f16x8_ma*)&qw[m2*16 + lm][eoff];
                    sacc[0][m2] = __builtin_amdgcn_mfma_f32_16x16x32_f16(aQ, bk[j][0], sacc[0][m2], 0,0,0);
                    sacc[1][m2] = __builtin_amdgcn_mfma_f32_16x16x32_f16(aQ, bk[j][1], sacc[1][m2], 0,0,0);
                }
            }
        }

        // ---- faithful mask (lane-local keys: k0 + h*256 + wv*16 + lm) ----
        float sv[2][4][4];
        #pragma unroll
        for (int h = 0; h < 2; ++h){
            const bool inval = (k0 + h*256 + wv*16 + lm) >= mk;
            #pragma unroll
            for (int m2 = 0; m2 < 4; ++m2)
                #pragma unroll
                for (int r = 0; r < 4; ++r)
                    sv[h][m2][r] = inval ? MASK_VALUE : sacc[h][m2][r];
        }

        // ---- per-wave row max over its 32 keys, publish ----
        float pm[4][4];
        #pragma unroll
        for (int m2 = 0; m2 < 4; ++m2)
            #pragma unroll
            for (int r = 0; r < 4; ++r) pm[m2][r] = fmaxf(sv[0][m2][r], sv[1][m2][r]);
        #pragma unroll
        for (int off = 1; off < 16; off <<= 1)
            #pragma unroll
            for (int m2 = 0; m2 < 4; ++m2)
                #pragma unroll
                for (int r = 0; r < 4; ++r)
                    pm[m2][r] = fmaxf(pm[m2][r], __shfl_xor(pm[m2][r], off, 64));
        if (lm == 0){
            #pragma unroll
            for (int m2 = 0; m2 < 4; ++m2)
                #pragma unroll
                for (int r = 0; r < 4; ++r) wredA[m2*16 + lg*4 + r][wv] = pm[m2][r];
        }
        __syncthreads();

        // ---- mnew + exact defer-max rescale + p -> fp16 LDS (both halves) ----
        #pragma unroll
        for (int m2 = 0; m2 < 4; ++m2)
            #pragma unroll
            for (int r = 0; r < 4; ++r){
                const int row = m2*16 + lg*4 + r;
                const f32x4 g0 = *(const f32x4_ma*)&wredA[row][0];
                const f32x4 g1 = *(const f32x4_ma*)&wredA[row][4];
                const f32x4 g2 = *(const f32x4_ma*)&wredA[row][8];
                const f32x4 g3 = *(const f32x4_ma*)&wredA[row][12];
                float gm = fmaxf(fmaxf(fmaxf(g0[0],g0[1]),fmaxf(g0[2],g0[3])),
                                 fmaxf(fmaxf(g1[0],g1[1]),fmaxf(g1[2],g1[3])));
                gm = fmaxf(gm, fmaxf(fmaxf(fmaxf(g2[0],g2[1]),fmaxf(g2[2],g2[3])),
                                     fmaxf(fmaxf(g3[0],g3[1]),fmaxf(g3[2],g3[3]))));
                if (gm > m_run[m2][r]){          // exact skip: fsc==1 when gm<=m_run
                    const float fsc = __expf(m_run[m2][r] - gm);
                    m_run[m2][r] = gm;
                    o_acc[m2][0][r] *= fsc;
                    o_acc[m2][1][r] *= fsc;
                    l_acc[m2][r]    *= fsc;
                }
                p_b[row][wv*16 + lm]       = (_Float16)__expf(sv[0][m2][r] - m_run[m2][r]);
                p_b[row][256 + wv*16 + lm] = (_Float16)__expf(sv[1][m2][r] - m_run[m2][r]);
            }
        __syncthreads();

        // ---- PV + ones-MFMA denominator over 16 key-blocks of 32 ----
        #pragma unroll
        for (int kb = 0; kb < 16; ++kb){
            f16x8 pa[4];
            #pragma unroll
            for (int m2 = 0; m2 < 4; ++m2)
                pa[m2] = *(const f16x8_ma*)&p_b[m2*16 + lm][kb*32 + lg*8];
            #pragma unroll
            for (int n = 0; n < 2; ++n){
                const f16x8 vv = *(const f16x8_ma*)(Vt + vbase + (size_t)n*16*NK + k0 + kb*32);
                #pragma unroll
                for (int m2 = 0; m2 < 4; ++m2)
                    o_acc[m2][n] = __builtin_amdgcn_mfma_f32_16x16x32_f16(pa[m2], vv, o_acc[m2][n], 0,0,0);
            }
            #pragma unroll
            for (int m2 = 0; m2 < 4; ++m2)
                l_acc[m2] = __builtin_amdgcn_mfma_f32_16x16x32_f16(pa[m2], ones, l_acc[m2], 0,0,0);
        }
    }

    // ===== epilogue: normalize with the consistent denominator =====
    #pragma unroll
    for (int m2 = 0; m2 < 4; ++m2){
        float li[4];
        #pragma unroll
        for (int r = 0; r < 4; ++r) li[r] = 1.f / l_acc[m2][r];
        #pragma unroll
        for (int n = 0; n < 2; ++n)
            #pragma unroll
            for (int r = 0; r < 4; ++r)
                Op[((size_t)b*NQ + q0 + m2*16 + lg*4 + r)*ND + wv*32 + n*16 + lm]
                    = o_acc[m2][n][r] * li[r];
    }
}

extern "C" void kernel_launch(void* const* d_in, const int* in_sizes, int n_in,
                              void* d_out, int out_size, void* d_ws, size_t ws_size,
                              hipStream_t stream)
{
    (void)in_sizes; (void)n_in; (void)out_size; (void)ws_size;
    const float* Qp = (const float*)d_in[0];
    const float* Kp = (const float*)d_in[1];
    const float* Vp = (const float*)d_in[2];
    const float* Wp = (const float*)d_in[3];
    const int*   Mp = (const int*)  d_in[4];
    float* Op = (float*)d_out;

    unsigned short* wsu = (unsigned short*)d_ws;   // 34.6 MB total
    _Float16*       Kf  = (_Float16*)wsu;
    _Float16*       Vt  = (_Float16*)(wsu + PLANE);
    unsigned short* Wth = wsu + 2*PLANE;
    unsigned short* Wtl = wsu + 2*PLANE + WPLANE;

    hipLaunchKernelGGL(conv_k_f16_kernel, dim3(PLANE/1024), dim3(256), 0, stream,
                       Kp, Kf);
    hipLaunchKernelGGL(transpose_v_f16_kernel, dim3(NB*32*8), dim3(256), 0, stream,
                       Vp, Vt);
    hipLaunchKernelGGL(transpose_split_w_kernel, dim3(64), dim3(256), 0, stream,
                       Wp, Wth, Wtl);
    hipLaunchKernelGGL(attn_kernel, dim3(NB*(NQ/QB)), dim3(1024), 0, stream,
                       Qp, Mp, Kf, Vt, Wth, Wtl, Op);
}